// Round 5
// baseline (1166.919 us; speedup 1.0000x reference)
//
#include <hip/hip_runtime.h>
#include <math.h>
#include <cstdint>
#include <cstddef>

#define NB 64
#define NH 1024
#define NS 2048
#define NV 50000
#define NH2 2048
#define NH3 3072

// workspace layout (float offsets)
#define OFF_GI      0                        // B x 3H
#define OFF_GH      (NB*NH3)                 // B x 3H
#define OFF_HNEW    (2*NB*NH3)               // B x H
#define OFF_SCORES  (OFF_HNEW + NB*NH)       // B x S (raw scores)
#define OFF_ML      (OFF_SCORES + NB*NS)     // B x 16 x {m,l}
#define OFF_PCTX    (OFF_ML + NB*16*2)       // B x 16 x H partial contexts
#define OFF_CONTEXT (OFF_PCTX + NB*16*NH)    // B x H
#define OFF_CRAW    (OFF_CONTEXT + NB*NH)    // B x H raw concat sums (atomic)
#define OFF_COUT    (OFF_CRAW + NB*NH)       // B x H tanh(concat)
// total = OFF_COUT + NB*NH = 1,837,056 floats = 7.35 MB

// ---------------------------------------------------------------------------
// K1: gi = x @ w_ih^T, gh = h @ w_hh^T   (x = embedding[input_seq])
// grid: 96 j-tiles x 2 matrices; block 256. Tile 64b x 32j, K-chunk 32.
// ---------------------------------------------------------------------------
__global__ __launch_bounds__(256) void gates_gemm(
    const int* __restrict__ seq, const float* __restrict__ lh,
    const float* __restrict__ emb, const float* __restrict__ wih,
    const float* __restrict__ whh, float* __restrict__ ws)
{
  __shared__ __align__(16) float As[32][66];   // [k][b]
  __shared__ __align__(16) float Ws[32][36];   // [k][j]
  __shared__ int seqs[64];
  const int tid = threadIdx.x;
  const int mat = blockIdx.x / 96;             // 0: gi, 1: gh
  const int j0  = (blockIdx.x % 96) * 32;
  const float* __restrict__ W = mat ? whh : wih;
  float* __restrict__ outp = ws + (mat ? OFF_GH : OFF_GI);
  if (tid < 64) seqs[tid] = mat ? 0 : seq[tid];
  __syncthreads();
  const int vx  = tid & 7;    // 8 j-groups of 4
  const int bxx = tid >> 3;   // 32 b-groups of 2
  float acc[2][4] = {{0.f,0.f,0.f,0.f},{0.f,0.f,0.f,0.f}};
  for (int kt = 0; kt < NH; kt += 32) {
    #pragma unroll
    for (int f = tid; f < 512; f += 256) {     // stage A: 64b x 32k
      const int bb = f >> 3, k4 = f & 7;
      const float* arow = mat ? (lh + (size_t)bb * NH)
                              : (emb + (size_t)seqs[bb] * NH);
      const float4 a = *(const float4*)(arow + kt + k4 * 4);
      As[k4*4+0][bb] = a.x; As[k4*4+1][bb] = a.y;
      As[k4*4+2][bb] = a.z; As[k4*4+3][bb] = a.w;
    }
    {                                          // stage W: 32j x 32k
      const int j = tid >> 3, k4 = tid & 7;
      const float4 w = *(const float4*)(W + (size_t)(j0 + j) * NH + kt + k4 * 4);
      Ws[k4*4+0][j] = w.x; Ws[k4*4+1][j] = w.y;
      Ws[k4*4+2][j] = w.z; Ws[k4*4+3][j] = w.w;
    }
    __syncthreads();
    #pragma unroll 8
    for (int k = 0; k < 32; ++k) {
      const float2 a = *(const float2*)&As[k][bxx*2];
      const float4 w = *(const float4*)&Ws[k][vx*4];
      acc[0][0] += a.x*w.x; acc[0][1] += a.x*w.y;
      acc[0][2] += a.x*w.z; acc[0][3] += a.x*w.w;
      acc[1][0] += a.y*w.x; acc[1][1] += a.y*w.y;
      acc[1][2] += a.y*w.z; acc[1][3] += a.y*w.w;
    }
    __syncthreads();
  }
  #pragma unroll
  for (int i = 0; i < 2; ++i)
    #pragma unroll
    for (int jj = 0; jj < 4; ++jj)
      outp[(size_t)(bxx*2 + i) * NH3 + j0 + vx*4 + jj] = acc[i][jj];
}

// ---------------------------------------------------------------------------
// K2: GRU gate combine -> h_new (ws) and hidden output (d_out)
// ---------------------------------------------------------------------------
__global__ __launch_bounds__(256) void gru_combine(
    const float* __restrict__ lh, const float* __restrict__ bih,
    const float* __restrict__ bhh, float* __restrict__ ws,
    float* __restrict__ hid_out)
{
  const int i = blockIdx.x * 256 + threadIdx.x;     // B*H
  const int b = i >> 10, j = i & (NH - 1);
  const float* gi = ws + OFF_GI + (size_t)b * NH3;
  const float* gh = ws + OFF_GH + (size_t)b * NH3;
  const float ir  = gi[j]        + bih[j],        hr = gh[j]        + bhh[j];
  const float iz  = gi[NH + j]   + bih[NH + j],   hz = gh[NH + j]   + bhh[NH + j];
  const float in_ = gi[2*NH + j] + bih[2*NH + j], hn = gh[2*NH + j] + bhh[2*NH + j];
  const float r = 1.f / (1.f + __expf(-(ir + hr)));
  const float z = 1.f / (1.f + __expf(-(iz + hz)));
  const float n = tanhf(in_ + r * hn);
  const float hnew = (1.f - z) * n + z * lh[i];
  ws[OFF_HNEW + i] = hnew;
  hid_out[i] = hnew;
}

// ---------------------------------------------------------------------------
// K3: fused scores + online-softmax + context partial, ONE pass over enc.
// grid: B*16 (b, s-chunk of 128); block 256 = 4 waves, each wave 32 s-rows.
// ---------------------------------------------------------------------------
__global__ __launch_bounds__(256) void attn_pass(
    const float* __restrict__ enc, float* __restrict__ ws)
{
  __shared__ __align__(16) float csh[4][NH];
  __shared__ float wm[4], wl[4];
  const int tid = threadIdx.x;
  const int b     = blockIdx.x >> 4;
  const int chunk = blockIdx.x & 15;
  const int wave  = tid >> 6;
  const int lane  = tid & 63;
  const float4* __restrict__ hn4 = (const float4*)(ws + OFF_HNEW + (size_t)b * NH);
  float4 h4[4];
  #pragma unroll
  for (int r = 0; r < 4; ++r) h4[r] = hn4[r*64 + lane];
  float m = -INFINITY, lsum = 0.f;
  float4 ctx[4];
  #pragma unroll
  for (int r = 0; r < 4; ++r) ctx[r] = make_float4(0.f,0.f,0.f,0.f);
  float* __restrict__ scores = ws + OFF_SCORES + (size_t)b * NS;
  const int s0 = chunk * 128 + wave * 32;
  for (int i = 0; i < 32; ++i) {
    const int s = s0 + i;
    const float4* __restrict__ e4 = (const float4*)(enc + ((size_t)s * NB + b) * NH);
    float4 e[4];
    #pragma unroll
    for (int r = 0; r < 4; ++r) e[r] = e4[r*64 + lane];   // coalesced 1KB/instr
    float d = 0.f;
    #pragma unroll
    for (int r = 0; r < 4; ++r)
      d += e[r].x*h4[r].x + e[r].y*h4[r].y + e[r].z*h4[r].z + e[r].w*h4[r].w;
    #pragma unroll
    for (int off = 32; off; off >>= 1) d += __shfl_xor(d, off);
    if (d > m) {                         // wave-uniform (d identical after reduce)
      const float sc = __expf(m - d);    // exp(-inf)=0 handles first row
      lsum *= sc;
      #pragma unroll
      for (int r = 0; r < 4; ++r) {
        ctx[r].x *= sc; ctx[r].y *= sc; ctx[r].z *= sc; ctx[r].w *= sc;
      }
      m = d;
    }
    const float p = __expf(d - m);
    lsum += p;
    #pragma unroll
    for (int r = 0; r < 4; ++r) {
      ctx[r].x += p * e[r].x; ctx[r].y += p * e[r].y;
      ctx[r].z += p * e[r].z; ctx[r].w += p * e[r].w;
    }
    if (lane == 0) scores[s] = d;
  }
  // merge the 4 wave partials inside the block -> one partial per (b,chunk)
  float4* csh4 = (float4*)csh[wave];
  #pragma unroll
  for (int r = 0; r < 4; ++r) csh4[r*64 + lane] = ctx[r];
  if (lane == 0) { wm[wave] = m; wl[wave] = lsum; }
  __syncthreads();
  const float m0 = wm[0], m1 = wm[1], m2 = wm[2], m3 = wm[3];
  const float M  = fmaxf(fmaxf(m0, m1), fmaxf(m2, m3));
  const float f0 = __expf(m0 - M), f1 = __expf(m1 - M),
              f2 = __expf(m2 - M), f3 = __expf(m3 - M);
  const float lout = f0*wl[0] + f1*wl[1] + f2*wl[2] + f3*wl[3];
  const float4 a0 = ((const float4*)csh[0])[tid];
  const float4 a1 = ((const float4*)csh[1])[tid];
  const float4 a2 = ((const float4*)csh[2])[tid];
  const float4 a3 = ((const float4*)csh[3])[tid];
  float4 o;
  o.x = f0*a0.x + f1*a1.x + f2*a2.x + f3*a3.x;
  o.y = f0*a0.y + f1*a1.y + f2*a2.y + f3*a3.y;
  o.z = f0*a0.z + f1*a1.z + f2*a2.z + f3*a3.z;
  o.w = f0*a0.w + f1*a1.w + f2*a2.w + f3*a3.w;
  ((float4*)(ws + OFF_PCTX + ((size_t)b*16 + chunk) * NH))[tid] = o;
  if (tid == 0) {
    ws[OFF_ML + (b*16 + chunk)*2 + 0] = M;
    ws[OFF_ML + (b*16 + chunk)*2 + 1] = lout;
  }
}

// ---------------------------------------------------------------------------
// K4: finalize softmax: merge 16 partials/b, write context + attn_weights.
// grid: B blocks x 256.
// ---------------------------------------------------------------------------
__global__ __launch_bounds__(256) void attn_finalize(
    float* __restrict__ ws, float* __restrict__ attn_out)
{
  __shared__ float fC[16];
  __shared__ float Msh, iLsh;
  const int tid = threadIdx.x;
  const int b = blockIdx.x;
  if (tid < 16) {
    const float mc = ws[OFF_ML + (b*16 + tid)*2 + 0];
    const float lc = ws[OFF_ML + (b*16 + tid)*2 + 1];
    float M = mc;
    #pragma unroll
    for (int off = 8; off; off >>= 1) M = fmaxf(M, __shfl_xor(M, off, 16));
    float L = lc * __expf(mc - M);
    #pragma unroll
    for (int off = 8; off; off >>= 1) L += __shfl_xor(L, off, 16);
    fC[tid] = __expf(mc - M) / L;
    if (tid == 0) { Msh = M; iLsh = 1.f / L; }
  }
  __syncthreads();
  const float M = Msh, iL = iLsh;
  const float4* __restrict__ p4 = (const float4*)(ws + OFF_PCTX + (size_t)b*16*NH);
  float4 acc = make_float4(0.f,0.f,0.f,0.f);
  #pragma unroll
  for (int c = 0; c < 16; ++c) {
    const float4 v = p4[c*256 + tid];
    const float f = fC[c];
    acc.x += f*v.x; acc.y += f*v.y; acc.z += f*v.z; acc.w += f*v.w;
  }
  ((float4*)(ws + OFF_CONTEXT + (size_t)b*NH))[tid] = acc;
  const float* __restrict__ sc = ws + OFF_SCORES + (size_t)b*NS;
  for (int s = tid; s < NS; s += 256)
    attn_out[(size_t)b*NS + s] = __expf(sc[s] - M) * iL;
}

// ---------------------------------------------------------------------------
// K5: concat GEMM (raw sums, k-split x4 via atomics into zeroed OFF_CRAW)
// grid: 64 j-tiles x 4 k-splits; block 256. A = [h_new | context].
// ---------------------------------------------------------------------------
__global__ __launch_bounds__(256) void concat_gemm(
    const float* __restrict__ cw, float* __restrict__ ws)
{
  __shared__ __align__(16) float As[32][66];
  __shared__ __align__(16) float Ws[32][20];
  const int tid = threadIdx.x;
  const int jt = blockIdx.x & 63;
  const int ks = blockIdx.x >> 6;
  const int j0 = jt * 16;
  const float* __restrict__ A = (ks < 2) ? (ws + OFF_HNEW) : (ws + OFF_CONTEXT);
  const int kbase = (ks & 1) * 512;  // offset within the selected half
  const int kg0   = ks * 512;        // offset within cw's 2048 columns
  const int vx = tid & 3;
  const int bb = tid >> 2;
  float acc[4] = {0.f,0.f,0.f,0.f};
  for (int kt = 0; kt < 512; kt += 32) {
    #pragma unroll
    for (int f = tid; f < 512; f += 256) {
      const int b_ = f >> 3, k4 = f & 7;
      const float4 a = *(const float4*)(A + (size_t)b_ * NH + kbase + kt + k4*4);
      As[k4*4+0][b_] = a.x; As[k4*4+1][b_] = a.y;
      As[k4*4+2][b_] = a.z; As[k4*4+3][b_] = a.w;
    }
    if (tid < 128) {
      const int j = tid >> 3, k4 = tid & 7;
      const float4 w = *(const float4*)(cw + (size_t)(j0 + j)*NH2 + kg0 + kt + k4*4);
      Ws[k4*4+0][j] = w.x; Ws[k4*4+1][j] = w.y;
      Ws[k4*4+2][j] = w.z; Ws[k4*4+3][j] = w.w;
    }
    __syncthreads();
    #pragma unroll 8
    for (int k = 0; k < 32; ++k) {
      const float a = As[k][bb];
      const float4 w = *(const float4*)&Ws[k][vx*4];
      acc[0] += a*w.x; acc[1] += a*w.y; acc[2] += a*w.z; acc[3] += a*w.w;
    }
    __syncthreads();
  }
  float* __restrict__ craw = ws + OFF_CRAW;
  #pragma unroll
  for (int jj = 0; jj < 4; ++jj)
    atomicAdd(&craw[(size_t)bb * NH + j0 + vx*4 + jj], acc[jj]);
}

// K5b: tanh + bias
__global__ __launch_bounds__(256) void concat_act(
    const float* __restrict__ cb, float* __restrict__ ws)
{
  const int i = blockIdx.x * 256 + threadIdx.x;
  ws[OFF_COUT + i] = tanhf(ws[OFF_CRAW + i] + cb[i & (NH-1)]);
}

// ---------------------------------------------------------------------------
// K6: output GEMM 64x1024 @ 1024x50000 (f32 vector; no f32 MFMA on CDNA4).
// Tile 64b x 128v, thread tile 8b x 4v, K-chunk 32. grid: 391 blocks.
// ---------------------------------------------------------------------------
__global__ __launch_bounds__(256) void out_gemm(
    const float* __restrict__ ow, const float* __restrict__ ob,
    const float* __restrict__ ws, float* __restrict__ out)
{
  __shared__ __align__(16) float As[32][68];    // [k][b]
  __shared__ __align__(16) float Wt[32][132];   // [k][v]
  const int tid = threadIdx.x;
  const int v0  = blockIdx.x * 128;
  const int vx  = tid & 31;   // 32 v-groups of 4
  const int bxx = tid >> 5;   // 8 b-groups of 8
  const float* __restrict__ A = ws + OFF_COUT;
  float acc[8][4];
  #pragma unroll
  for (int i = 0; i < 8; ++i)
    #pragma unroll
    for (int j = 0; j < 4; ++j) acc[i][j] = 0.f;
  for (int kt = 0; kt < NH; kt += 32) {
    #pragma unroll
    for (int f = tid; f < 512; f += 256) {      // stage A: 64b x 32k
      const int b_ = f >> 3, k4 = f & 7;
      const float4 a = *(const float4*)(A + (size_t)b_ * NH + kt + k4*4);
      As[k4*4+0][b_] = a.x; As[k4*4+1][b_] = a.y;
      As[k4*4+2][b_] = a.z; As[k4*4+3][b_] = a.w;
    }
    #pragma unroll
    for (int f = tid; f < 1024; f += 256) {     // stage W: 128v x 32k (guarded)
      const int v_ = f >> 3, k4 = f & 7;
      float4 w = make_float4(0.f,0.f,0.f,0.f);
      if (v0 + v_ < NV)
        w = *(const float4*)(ow + (size_t)(v0 + v_) * NH + kt + k4*4);
      Wt[k4*4+0][v_] = w.x; Wt[k4*4+1][v_] = w.y;
      Wt[k4*4+2][v_] = w.z; Wt[k4*4+3][v_] = w.w;
    }
    __syncthreads();
    #pragma unroll 8
    for (int k = 0; k < 32; ++k) {
      const float4 a0 = *(const float4*)&As[k][bxx*8];
      const float4 a1 = *(const float4*)&As[k][bxx*8 + 4];
      const float4 w  = *(const float4*)&Wt[k][vx*4];
      acc[0][0] += a0.x*w.x; acc[0][1] += a0.x*w.y; acc[0][2] += a0.x*w.z; acc[0][3] += a0.x*w.w;
      acc[1][0] += a0.y*w.x; acc[1][1] += a0.y*w.y; acc[1][2] += a0.y*w.z; acc[1][3] += a0.y*w.w;
      acc[2][0] += a0.z*w.x; acc[2][1] += a0.z*w.y; acc[2][2] += a0.z*w.z; acc[2][3] += a0.z*w.w;
      acc[3][0] += a0.w*w.x; acc[3][1] += a0.w*w.y; acc[3][2] += a0.w*w.z; acc[3][3] += a0.w*w.w;
      acc[4][0] += a1.x*w.x; acc[4][1] += a1.x*w.y; acc[4][2] += a1.x*w.z; acc[4][3] += a1.x*w.w;
      acc[5][0] += a1.y*w.x; acc[5][1] += a1.y*w.y; acc[5][2] += a1.y*w.z; acc[5][3] += a1.y*w.w;
      acc[6][0] += a1.z*w.x; acc[6][1] += a1.z*w.y; acc[6][2] += a1.z*w.z; acc[6][3] += a1.z*w.w;
      acc[7][0] += a1.w*w.x; acc[7][1] += a1.w*w.y; acc[7][2] += a1.w*w.z; acc[7][3] += a1.w*w.w;
    }
    __syncthreads();
  }
  #pragma unroll
  for (int i = 0; i < 8; ++i) {
    const int b_ = bxx*8 + i;
    #pragma unroll
    for (int j = 0; j < 4; ++j) {
      const int v = v0 + vx*4 + j;
      if (v < NV) out[(size_t)b_ * NV + v] = acc[i][j] + ob[v];
    }
  }
}

// ---------------------------------------------------------------------------
extern "C" void kernel_launch(void* const* d_in, const int* in_sizes, int n_in,
                              void* d_out, int out_size, void* d_ws, size_t ws_size,
                              hipStream_t stream)
{
  const int*   seq = (const int*)d_in[0];
  const float* lh  = (const float*)d_in[1];
  const float* enc = (const float*)d_in[2];
  const float* emb = (const float*)d_in[3];
  const float* wih = (const float*)d_in[4];
  const float* whh = (const float*)d_in[5];
  const float* bih = (const float*)d_in[6];
  const float* bhh = (const float*)d_in[7];
  const float* cw  = (const float*)d_in[8];
  const float* cb  = (const float*)d_in[9];
  const float* ow  = (const float*)d_in[10];
  const float* ob  = (const float*)d_in[11];
  float* out = (float*)d_out;
  float* ws  = (float*)d_ws;

  // zero the atomic accumulation region (ws is poisoned 0xAA before each call)
  hipMemsetAsync(ws + OFF_CRAW, 0, (size_t)NB * NH * sizeof(float), stream);

  gates_gemm   <<<dim3(192),  dim3(256), 0, stream>>>(seq, lh, emb, wih, whh, ws);
  gru_combine  <<<dim3(256),  dim3(256), 0, stream>>>(lh, bih, bhh, ws,
                                                      out + (size_t)NB * NV);
  attn_pass    <<<dim3(1024), dim3(256), 0, stream>>>(enc, ws);
  attn_finalize<<<dim3(64),   dim3(256), 0, stream>>>(ws,
                                                      out + (size_t)NB * NV + NB * NH);
  concat_gemm  <<<dim3(256),  dim3(256), 0, stream>>>(cw, ws);
  concat_act   <<<dim3(256),  dim3(256), 0, stream>>>(cb, ws);
  out_gemm     <<<dim3(391),  dim3(256), 0, stream>>>(ow, ob, ws, out);
}